// Round 4
// baseline (35.115 us; speedup 1.0000x reference)
//
#include <hip/hip_runtime.h>

// out[r,s,j,a] = sum_b skts[r,j,a,b] * pts_h[r,s,b],  a in 0..2
// pts:  [R=4096, S=96, 3]   f32
// skts: [R=4096, J=24, 4,4] f32
// out:  [R, S, J, 3]        f32  (113 MB -> store-bound)
//
// v4: LDS-issue debottleneck. v2 did 15 ds_read_b32 per 12B output (~87 LDS
// cyc per 768B/wave > 68-cyc budget at fill rate -> 5.2 TB/s cap, matches
// measurement). Now each thread makes 12 contiguous floats (one s, 4 j's)
// from 4 ds_read_b128 per 48B output (~2 cyc/100B). Stores: 3x dwordx4,
// 16B-aligned. BLOCK=384, RPB=2 -> 1152 units / 384 = 3 iters, no tail.

constexpr int S_DIM = 96;
constexpr int J_DIM = 24;
constexpr int BLOCK = 384;                 // 6 waves
constexpr int RPB   = 2;
constexpr int SKT_STR   = 20;              // words per j-row (12 used, pad->20: 80B = 16B-aligned, 3-way banks max)
constexpr int SKT_WORDS = J_DIM * SKT_STR; // 480 per ray
constexpr int PTS_WORDS = S_DIM * 4;       // 384 per ray: [s][4], w slot unused pad
constexpr int UNITS = RPB * S_DIM * J_DIM * 3 / 12;   // 1152 12-float units per block
constexpr int ITERS = UNITS / BLOCK;       // 3
constexpr int RAY_FLOATS = S_DIM * J_DIM * 3;         // 6912

__global__ __launch_bounds__(BLOCK) void w2l_kernel(
    const float* __restrict__ pts,
    const float* __restrict__ skts,
    float* __restrict__ out) {

    const int tid = threadIdx.x;
    const int r0  = blockIdx.x * RPB;

    __shared__ __align__(16) float s_skt[RPB][SKT_WORDS];
    __shared__ __align__(16) float s_pts[RPB][PTS_WORDS];

    // ---- stage both rays (skt: 192 float4; pts: 576 scalars scattered to [s][4]) ----
    const float* __restrict__ skt_g = skts + (size_t)r0 * (J_DIM * 16);
    const float* __restrict__ pts_g = pts  + (size_t)r0 * (S_DIM * 3);

    if (tid < RPB * 96) {                       // 96 float4 per ray, rays contiguous
        float4 v = reinterpret_cast<const float4*>(skt_g)[tid];
        int ray = tid / 96, g = tid - ray * 96; // g = j*4 + a
        int j = g >> 2, a = g & 3;
        *reinterpret_cast<float4*>(&s_skt[ray][j * SKT_STR + a * 4]) = v;
        // also seed w=1 pad slots (192 of them, one per (ray,s))
        int s = tid % S_DIM, ray2 = tid / S_DIM;
        s_pts[ray2][s * 4 + 3] = 1.0f;
    }
    #pragma unroll
    for (int q = tid; q < RPB * S_DIM * 3; q += BLOCK) {  // 576 scalars
        float v = pts_g[q];
        int ray = q / (S_DIM * 3), qq = q - ray * (S_DIM * 3);
        int s = qq / 3, c = qq - s * 3;
        s_pts[ray][s * 4 + c] = v;
    }
    __syncthreads();

    // ---- compute + store: unit u -> 12 contiguous output floats ----
    float* __restrict__ out_p = out + (size_t)r0 * RAY_FLOATS;

    #pragma unroll
    for (int it = 0; it < ITERS; ++it) {
        const int u   = tid + it * BLOCK;          // 0..1151
        const int ray = u / 576;
        const int up  = u - ray * 576;             // unit within ray
        const int s   = up / 6;                    // 6 units per s
        const int jstart = (up - s * 6) * 4;       // 4 j's per unit

        const float4 P = *reinterpret_cast<const float4*>(&s_pts[ray][s * 4]);
        const float* __restrict__ base = &s_skt[ray][jstart * SKT_STR];

        float o12[12];
        #pragma unroll
        for (int jj = 0; jj < 4; ++jj) {
            const float4 B0 = *reinterpret_cast<const float4*>(base + jj * SKT_STR + 0);
            const float4 B1 = *reinterpret_cast<const float4*>(base + jj * SKT_STR + 4);
            const float4 B2 = *reinterpret_cast<const float4*>(base + jj * SKT_STR + 8);
            o12[jj * 3 + 0] = fmaf(B0.x, P.x, fmaf(B0.y, P.y, fmaf(B0.z, P.z, B0.w)));
            o12[jj * 3 + 1] = fmaf(B1.x, P.x, fmaf(B1.y, P.y, fmaf(B1.z, P.z, B1.w)));
            o12[jj * 3 + 2] = fmaf(B2.x, P.x, fmaf(B2.y, P.y, fmaf(B2.z, P.z, B2.w)));
        }

        float* __restrict__ dst = out_p + (size_t)u * 12;   // 48B-aligned
        #pragma unroll
        for (int k = 0; k < 3; ++k) {
            *reinterpret_cast<float4*>(dst + 4 * k) =
                make_float4(o12[4 * k], o12[4 * k + 1], o12[4 * k + 2], o12[4 * k + 3]);
        }
    }
}

extern "C" void kernel_launch(void* const* d_in, const int* in_sizes, int n_in,
                              void* d_out, int out_size, void* d_ws, size_t ws_size,
                              hipStream_t stream) {
    const float* pts  = (const float*)d_in[0];
    const float* skts = (const float*)d_in[1];
    float* out = (float*)d_out;

    const int R = in_sizes[0] / (S_DIM * 3);   // 4096
    w2l_kernel<<<R / RPB, BLOCK, 0, stream>>>(pts, skts, out);
}

// Round 5
// 24.203 us; speedup vs baseline: 1.4509x; 1.4509x over previous
//
#include <hip/hip_runtime.h>

// out[r,s,j,a] = sum_b skts[r,j,a,b] * pts_h[r,s,b],  a in 0..2
// pts:  [R=4096, S=96, 3]   f32
// skts: [R=4096, J=24, 4,4] f32
// out:  [R, S, J, 3]        f32  (113 MB -> store-bound)
//
// v5: BLOCK=384 => j = tid%24 invariant across iterations -> matrix rows live
// in 12 registers, loaded once per ray via 3x ds_read_b128 (row stride 20
// words: quad = 5j mod 8 covers all 8 bank-quads). Inner loop = 1 ds_read_b128
// (pts[s][4], broadcast) + 12 fma + contiguous 12B store (v2's proven store
// mapping p = s*24+j). LDS issue: ~87 -> ~12 cyc per 768B/wave.

constexpr int S_DIM = 96;
constexpr int J_DIM = 24;
constexpr int BLOCK = 384;                  // 6 waves; 384 % 24 == 0
constexpr int RPB   = 2;
constexpr int SKT_STR   = 20;               // words/row: 80B stride -> 5j mod 8 quad sweep
constexpr int SKT_WORDS = J_DIM * SKT_STR;  // 480
constexpr int PTS_WORDS = S_DIM * 4;        // [s][4], w = 1.0 pad
constexpr int ITERS = S_DIM * J_DIM / BLOCK;        // 2304/384 = 6
constexpr int RAY_FLOATS = S_DIM * J_DIM * 3;       // 6912

__global__ __launch_bounds__(BLOCK) void w2l_kernel(
    const float* __restrict__ pts,
    const float* __restrict__ skts,
    float* __restrict__ out) {

    const int tid = threadIdx.x;
    const int r0  = blockIdx.x * RPB;

    __shared__ __align__(16) float s_skt[2][SKT_WORDS];
    __shared__ __align__(16) float s_pts[2][PTS_WORDS];

    const int s0 = tid / J_DIM;             // 0..15 (magic-mul, once)
    const int j  = tid - s0 * J_DIM;        // invariant j for this thread

    // staging: tid<96 -> one float4 of skt (+ seed w=1); tid>=96 -> one scalar of pts
    auto load_ray = [&](int r, float4& v, float& pv) {
        if (tid < 96) {
            v = reinterpret_cast<const float4*>(skts + (size_t)r * (J_DIM * 16))[tid];
        } else {
            pv = pts[(size_t)r * (S_DIM * 3) + (tid - 96)];   // 288 scalars, coalesced
        }
    };
    auto write_lds = [&](int buf, const float4& v, float pv) {
        if (tid < 96) {
            int jj = tid >> 2, a = tid & 3;                   // g = j*4 + a
            *reinterpret_cast<float4*>(&s_skt[buf][jj * SKT_STR + a * 4]) = v;
            s_pts[buf][tid * 4 + 3] = 1.0f;                   // w pad (tid == s)
        } else {
            int q = tid - 96;
            int sq = q / 3, c = q - 3 * sq;
            s_pts[buf][sq * 4 + c] = pv;
        }
    };

    float4 v; float pv;
    load_ray(r0, v, pv);
    write_lds(0, v, pv);
    __syncthreads();

    for (int rr = 0; rr < RPB; ++rr) {
        const int cur = rr & 1;
        float4 nv; float npv;
        if (rr + 1 < RPB) load_ray(r0 + rr + 1, nv, npv);     // in flight during stores

        // matrix rows -> registers, once per ray (3x b128, all 8 quads covered)
        const float4 B0 = *reinterpret_cast<const float4*>(&s_skt[cur][j * SKT_STR + 0]);
        const float4 B1 = *reinterpret_cast<const float4*>(&s_skt[cur][j * SKT_STR + 4]);
        const float4 B2 = *reinterpret_cast<const float4*>(&s_skt[cur][j * SKT_STR + 8]);

        float* __restrict__ out_r = out + (size_t)(r0 + rr) * RAY_FLOATS;

        #pragma unroll
        for (int it = 0; it < ITERS; ++it) {
            const int s = s0 + it * 16;
            const float4 P = *reinterpret_cast<const float4*>(&s_pts[cur][s * 4]);

            const float ox = fmaf(B0.x, P.x, fmaf(B0.y, P.y, fmaf(B0.z, P.z, B0.w)));
            const float oy = fmaf(B1.x, P.x, fmaf(B1.y, P.y, fmaf(B1.z, P.z, B1.w)));
            const float oz = fmaf(B2.x, P.x, fmaf(B2.y, P.y, fmaf(B2.z, P.z, B2.w)));

            const int p = tid + it * BLOCK;                   // consecutive lanes -> 12B stride
            *reinterpret_cast<float3*>(out_r + (size_t)p * 3) = make_float3(ox, oy, oz);
        }

        if (rr + 1 < RPB) {
            write_lds(cur ^ 1, nv, npv);
            __syncthreads();
        }
    }
}

extern "C" void kernel_launch(void* const* d_in, const int* in_sizes, int n_in,
                              void* d_out, int out_size, void* d_ws, size_t ws_size,
                              hipStream_t stream) {
    const float* pts  = (const float*)d_in[0];
    const float* skts = (const float*)d_in[1];
    float* out = (float*)d_out;

    const int R = in_sizes[0] / (S_DIM * 3);   // 4096
    w2l_kernel<<<R / RPB, BLOCK, 0, stream>>>(pts, skts, out);
}